// Round 7
// baseline (494.600 us; speedup 1.0000x reference)
//
#include <hip/hip_runtime.h>
#include <stdint.h>

// BatchTopK: x (1024, 65536) f32, keep global top k*1024 = 65536 of relu(x), zero rest.
//
// R12: overlap the read and write streams via role-split fusion, PLAIN stores.
// Model (R6-R11): dur = ~332us poison floor (2x 1GiB harness fills @6.5TB/s)
// + ~153us ours. Ours is serial {scan-read ~60-110} -> {memset-out ~40} ->
// {finish ~10} -> {scatter ~5}. The read and write streams are independent;
// combined mandatory HBM traffic is only ~400MB (131MB L3-assisted FETCH +
// 266MB WRITE) ~= 63us overlapped. hipEvent* is banned inside kernel_launch,
// so cross-stream fork is impossible -> fuse via role-split blocks.
// Failure autopsy honored: R6 fused-nt (208us, nt ~2TB/s cap) and R8
// per-wave-interleave (690us) both used nt stores / interleaved streams.
// Here: even 8-block granules = PURE zero blocks (plain float4 stores,
// exactly the 6.6TB/s fillBuffer pattern); odd granules = R11's scan.
// Single variable vs R11: hipMemsetAsync(out) deleted, roles fused.

#define HDR_CURSOR 0
#define HDR_FLAG   1
#define HDR_THR    2
#define HDR_ICUT   3
#define HIST_OFF   4096       // uint32 ghist[2048] at ws+4096
#define CAND_OFF   16384      // candidate buffer
#define NBINS      2048u
#define BUCKET_CAP 6144u
#define SCAN_STAGE 1024       // per-block candidate staging (expected ~88/block)
#define ROWS       1024u      // x.shape[0], fixed by the problem
#define SPEC       3.0f       // count(x>=3.0) ~ 90.6k >= K=65536
#define BASE_BITS  0x40400000u  // __float_as_uint(3.0f)

__device__ __forceinline__ uint32_t bin_of(uint32_t key) {
  uint32_t off = key - BASE_BITS;        // key >= BASE_BITS guaranteed by SPEC filter
  uint32_t b = off >> 12;
  return b < NBINS ? b : (NBINS - 1u);
}

__device__ __forceinline__ float max4(float4 a) {
  return fmaxf(fmaxf(a.x, a.y), fmaxf(a.z, a.w));
}

// Only used on the forced-fallback path (tiny workspace).
__global__ void k_init(uint32_t* hdr, uint32_t* ghist, uint32_t force_flag) {
  for (uint32_t i = threadIdx.x; i < 64u + NBINS; i += 256u) {
    if (i < 64u) hdr[i] = 0u;
    else ghist[i - 64u] = 0u;
  }
  if (threadIdx.x == 0u) hdr[HDR_FLAG] = force_flag;
}

__device__ __forceinline__ void push4(float4 a, uint32_t gi,
                                      uint32_t* s_cnt, uint2* s_buf) {
  if (a.x >= SPEC) { uint32_t p = atomicAdd(s_cnt, 1u); if (p < SCAN_STAGE) s_buf[p] = make_uint2(__float_as_uint(a.x), gi); }
  if (a.y >= SPEC) { uint32_t p = atomicAdd(s_cnt, 1u); if (p < SCAN_STAGE) s_buf[p] = make_uint2(__float_as_uint(a.y), gi + 1u); }
  if (a.z >= SPEC) { uint32_t p = atomicAdd(s_cnt, 1u); if (p < SCAN_STAGE) s_buf[p] = make_uint2(__float_as_uint(a.z), gi + 2u); }
  if (a.w >= SPEC) { uint32_t p = atomicAdd(s_cnt, 1u); if (p < SCAN_STAGE) s_buf[p] = make_uint2(__float_as_uint(a.w), gi + 3u); }
}

// Role-split fused kernel. Even 8-block granules: pure zero stream with PLAIN
// float4 stores (the 6.6 TB/s fillBuffer pattern). Odd granules: read-only
// scan, wave-contiguous 4-deep loads, LDS-staged candidates + linear hist.
__global__ __launch_bounds__(256) void k_scanzero(
    float4* __restrict__ out4, float* __restrict__ out,
    const float4* __restrict__ x4, const float* __restrict__ x,
    uint2* __restrict__ cand, uint32_t* __restrict__ hdr,
    uint32_t* __restrict__ ghist,
    uint32_t cap, uint32_t n4, uint32_t n, uint32_t half) {
  uint32_t g    = blockIdx.x >> 3;
  uint32_t role = g & 1u;                            // granule parity
  uint32_t bid  = (g >> 1) * 8u + (blockIdx.x & 7u); // index within role [0, half)
  uint32_t tid  = threadIdx.x;
  uint32_t tail0 = n4 * 4u;

  if (role == 0u) {
    // ---------------- pure zero stream: plain stores, fill pattern ----------------
    const float4 z = make_float4(0.f, 0.f, 0.f, 0.f);
    uint32_t stride = half * 256u;
#pragma unroll 4
    for (uint32_t i = bid * 256u + tid; i < n4; i += stride)
      out4[i] = z;
    if (bid == 0u && tid < (n - tail0))
      out[tail0 + tid] = 0.f;
    return;
  }

  // ---------------- scan stream: wave-contiguous 4-deep ----------------
  __shared__ uint32_t s_cnt;
  __shared__ uint32_t s_base;
  __shared__ uint2 s_buf[SCAN_STAGE];
  if (tid == 0u) s_cnt = 0u;
  __syncthreads();

  uint32_t lane = tid & 63u;
  uint32_t gwid = (bid * 256u + tid) >> 6;   // wave id within scan role
  uint32_t nw   = (half * 256u) >> 6;        // total scan waves
  uint32_t nchunk = n4 >> 8;                 // 256-float4 chunks
  for (uint32_t c = gwid; c < nchunk; c += nw) {
    uint32_t base = c << 8;
    float4 a0 = x4[base + lane];
    float4 a1 = x4[base + 64u + lane];
    float4 a2 = x4[base + 128u + lane];
    float4 a3 = x4[base + 192u + lane];
    if (__ballot(max4(a0) >= SPEC)) push4(a0, (base + lane) * 4u, &s_cnt, s_buf);
    if (__ballot(max4(a1) >= SPEC)) push4(a1, (base + 64u + lane) * 4u, &s_cnt, s_buf);
    if (__ballot(max4(a2) >= SPEC)) push4(a2, (base + 128u + lane) * 4u, &s_cnt, s_buf);
    if (__ballot(a3.x >= SPEC || a3.y >= SPEC || a3.z >= SPEC || a3.w >= SPEC ? 1 : 0))
      push4(a3, (base + 192u + lane) * 4u, &s_cnt, s_buf);
  }
  // remainder float4s (none for the bench shape) + scalar tail
  uint32_t rem0 = nchunk << 8;
  if (bid == 0u) {
    for (uint32_t i = rem0 + tid; i < n4; i += 256u) {
      float4 a = x4[i];
      if (__ballot(max4(a) >= SPEC)) push4(a, i * 4u, &s_cnt, s_buf);
    }
    if (tid < (n - tail0)) {
      uint32_t gi = tail0 + tid;
      float v = x[gi];
      if (v >= SPEC) { uint32_t p = atomicAdd(&s_cnt, 1u); if (p < SCAN_STAGE) s_buf[p] = make_uint2(__float_as_uint(v), gi); }
    }
  }
  __syncthreads();
  uint32_t cnt = s_cnt;
  if (cnt == 0u) return;
  uint32_t wcnt = cnt < (uint32_t)SCAN_STAGE ? cnt : (uint32_t)SCAN_STAGE;
  if (tid == 0u) {
    s_base = atomicAdd(&hdr[HDR_CURSOR], cnt);  // true total (drops flagged)
    if (cnt > (uint32_t)SCAN_STAGE) atomicOr(&hdr[HDR_FLAG], 1u);
  }
  __syncthreads();
  uint32_t base = s_base;
  for (uint32_t j = tid; j < wcnt; j += blockDim.x) {
    uint32_t gidx = base + j;
    if (gidx < cap) {
      uint2 c = s_buf[j];
      cand[gidx] = c;
      atomicAdd(&ghist[bin_of(c.x)], 1u);   // ~88/block, spread over 2048 words
    }
  }
  if (tid == 0u && base + wcnt > cap) atomicOr(&hdr[HDR_FLAG], 1u);
}

// Single block: select (2048-bin suffix scan + bucket collect + exact rank);
// on any abort, the exact full-radix fallback runs inline in the same block.
__global__ __launch_bounds__(1024) void k_finish(
    const uint2* __restrict__ cand, uint32_t* __restrict__ hdr,
    const uint32_t* __restrict__ ghist, const int* __restrict__ kptr,
    const float* __restrict__ x, float* __restrict__ out,
    uint32_t cap, uint32_t n) {
  __shared__ __align__(16) uint8_t smem[57344];          // 56 KB union
  uint32_t* h      = (uint32_t*)smem;                    // select hist / fb hist
  uint2*    bkt    = (uint2*)(smem + 8192);              // select bucket (48KB)
  uint32_t* eq_idx = (uint32_t*)(smem + 8192);           // fb eq-scan (16KB, aliases bkt)
  __shared__ uint32_t s_sel, s_rank, s_bcnt, s_need, s_found, s_eqcnt, s_icut;
  uint32_t tid = threadIdx.x;
  uint32_t K = (uint32_t)kptr[0] * ROWS;
  uint32_t M = hdr[HDR_CURSOR];
  if (tid == 0u) s_need = 0u;
  __syncthreads();

  // ---------------- select phase (block-uniform branching) ----------------
  bool skip_sel = (hdr[HDR_FLAG] != 0u || M > cap || M < K);
  if (skip_sel) {
    if (tid == 0u) s_need = 1u;
  } else if (K == 0u) {
    // keep nothing; candidate keys are finite positive floats < 0xFFFFFFFF
    if (tid == 0u) { hdr[HDR_THR] = 0xFFFFFFFFu; hdr[HDR_ICUT] = 0xFFFFFFFFu; }
    return;
  } else {
    h[tid] = ghist[tid];
    h[tid + 1024u] = ghist[tid + 1024u];
    if (tid == 0u) s_bcnt = 0u;
    __syncthreads();
    // wave 0: suffix scan over 2048 bins to find the bin holding rank K
    if (tid < 64u) {
      uint32_t seg = NBINS >> 6;           // 32 bins per lane
      uint32_t base = tid * seg;
      uint32_t lanesum = 0u;
      for (uint32_t j = 0; j < seg; ++j) lanesum += h[base + j];
      uint32_t s = lanesum;                // inclusive suffix scan across lanes
      for (int d = 1; d < 64; d <<= 1) {
        uint32_t v = (uint32_t)__shfl_down((int)s, d, 64);
        if ((int)tid + d < 64) s += v;
      }
      uint32_t above = s - lanesum;        // total count in lanes > tid
      if (above < K && above + lanesum >= K) {   // exactly one lane matches
        uint32_t r = K - above;
        uint32_t cum = 0u;
        for (int j = (int)seg - 1; j >= 0; --j) {
          uint32_t c = h[base + (uint32_t)j];
          if (cum + c >= r) { s_sel = base + (uint32_t)j; s_rank = r - cum; break; }
          cum += c;
        }
      }
    }
    __syncthreads();
    uint32_t bsel = s_sel;
    uint32_t r = s_rank;                   // 1-indexed rank inside the bin
    uint32_t E = h[bsel];
    if (bsel == NBINS - 1u || E > BUCKET_CAP) {  // clamp bin or oversized bucket
      if (tid == 0u) s_need = 1u;
    } else {
      // collect candidates in bin bsel (x4 unrolled, 8 keys/iter)
      const uint4* __restrict__ cand4 = (const uint4*)cand;
      uint32_t M2 = M >> 1;
      uint32_t j = tid;
      for (; j + 3072u < M2; j += 4096u) {
        uint4 c0 = cand4[j];
        uint4 c1 = cand4[j + 1024u];
        uint4 c2 = cand4[j + 2048u];
        uint4 c3 = cand4[j + 3072u];
        if (bin_of(c0.x) == bsel) { uint32_t p = atomicAdd(&s_bcnt, 1u); if (p < BUCKET_CAP) bkt[p] = make_uint2(c0.x, c0.y); }
        if (bin_of(c0.z) == bsel) { uint32_t p = atomicAdd(&s_bcnt, 1u); if (p < BUCKET_CAP) bkt[p] = make_uint2(c0.z, c0.w); }
        if (bin_of(c1.x) == bsel) { uint32_t p = atomicAdd(&s_bcnt, 1u); if (p < BUCKET_CAP) bkt[p] = make_uint2(c1.x, c1.y); }
        if (bin_of(c1.z) == bsel) { uint32_t p = atomicAdd(&s_bcnt, 1u); if (p < BUCKET_CAP) bkt[p] = make_uint2(c1.z, c1.w); }
        if (bin_of(c2.x) == bsel) { uint32_t p = atomicAdd(&s_bcnt, 1u); if (p < BUCKET_CAP) bkt[p] = make_uint2(c2.x, c2.y); }
        if (bin_of(c2.z) == bsel) { uint32_t p = atomicAdd(&s_bcnt, 1u); if (p < BUCKET_CAP) bkt[p] = make_uint2(c2.z, c2.w); }
        if (bin_of(c3.x) == bsel) { uint32_t p = atomicAdd(&s_bcnt, 1u); if (p < BUCKET_CAP) bkt[p] = make_uint2(c3.x, c3.y); }
        if (bin_of(c3.z) == bsel) { uint32_t p = atomicAdd(&s_bcnt, 1u); if (p < BUCKET_CAP) bkt[p] = make_uint2(c3.z, c3.w); }
      }
      for (; j < M2; j += 1024u) {
        uint4 c = cand4[j];
        if (bin_of(c.x) == bsel) { uint32_t p = atomicAdd(&s_bcnt, 1u); if (p < BUCKET_CAP) bkt[p] = make_uint2(c.x, c.y); }
        if (bin_of(c.z) == bsel) { uint32_t p = atomicAdd(&s_bcnt, 1u); if (p < BUCKET_CAP) bkt[p] = make_uint2(c.z, c.w); }
      }
      if (tid == 0u && (M & 1u)) {
        uint2 c = cand[M - 1u];
        if (bin_of(c.x) == bsel) { uint32_t p = atomicAdd(&s_bcnt, 1u); if (p < BUCKET_CAP) bkt[p] = c; }
      }
      __syncthreads();
      // exact selection: entry with composite rank r-1 (key desc, idx asc)
      for (uint32_t e = tid; e < E; e += 1024u) {
        uint2 me = bkt[e];
        uint32_t rank = 0u;
        for (uint32_t jj = 0; jj < E; ++jj) {
          uint2 o = bkt[jj];
          rank += (o.x > me.x || (o.x == me.x && o.y < me.y)) ? 1u : 0u;
        }
        if (rank == r - 1u) { hdr[HDR_THR] = me.x; hdr[HDR_ICUT] = me.y; }
      }
    }
  }
  __syncthreads();
  if (s_need == 0u) return;
  if (tid == 0u) hdr[HDR_FLAG] = 1u;   // k_scatter will skip

  // ---------------- exact fallback (inline, same block) ----------------
  uint32_t prefix = 0u;
  uint32_t R = K;
  bool zero_thr = (K == 0u);
  for (int lvl = 0; lvl < 3 && !zero_thr; ++lvl) {
    uint32_t shift = (lvl == 0) ? 21u : (lvl == 1 ? 10u : 0u);
    uint32_t nb = (lvl == 2) ? 1024u : 2048u;
    for (uint32_t b = tid; b < nb; b += 1024u) h[b] = 0u;
    __syncthreads();
    for (uint32_t i = tid; i < n; i += 1024u) {
      float v = x[i];
      uint32_t key = (v > 0.f) ? __float_as_uint(v) : 0u;
      bool valid = (key != 0u);
      if (lvl == 1) valid = valid && ((key >> 21) == prefix);
      if (lvl == 2) valid = valid && ((key >> 10) == prefix);
      if (valid) atomicAdd(&h[(key >> shift) & (nb - 1u)], 1u);
    }
    __syncthreads();
    if (tid == 0u) {
      uint32_t cum = 0u, sel = 0u, rr = R, found = 0u;
      for (int b = (int)nb - 1; b >= 0; --b) {
        uint32_t c = h[b];
        if (cum + c >= R) { sel = (uint32_t)b; rr = R - cum; found = 1u; break; }
        cum += c;
      }
      s_sel = sel; s_rank = rr; s_found = found;
    }
    __syncthreads();
    if (s_found == 0u) {
      zero_thr = true;  // fewer than K positives: keep all positives
    } else {
      uint32_t sel = s_sel;
      R = s_rank;
      if (lvl == 0) prefix = sel;
      else if (lvl == 1) prefix = (prefix << 11) | sel;
      else prefix = (prefix << 10) | sel;
    }
    __syncthreads();
  }
  uint32_t thr_key = zero_thr ? 0u : prefix;
  uint32_t icut = 0xFFFFFFFFu;
  if (!zero_thr) {
    uint32_t E2 = h[thr_key & 1023u];
    uint32_t T = R;
    if (T < E2) {
      if (tid == 0u) { s_eqcnt = 0u; s_icut = 0xFFFFFFFFu; }
      __syncthreads();
      for (uint32_t i = tid; i < n; i += 1024u) {
        float v = x[i];
        if (v > 0.f && __float_as_uint(v) == thr_key) {
          uint32_t p = atomicAdd(&s_eqcnt, 1u);
          if (p < 4096u) eq_idx[p] = i;
        }
      }
      __syncthreads();
      uint32_t ec = s_eqcnt < 4096u ? s_eqcnt : 4096u;
      for (uint32_t e = tid; e < ec; e += 1024u) {
        uint32_t me = eq_idx[e];
        uint32_t rank = 0u;
        for (uint32_t j = 0; j < ec; ++j) rank += (eq_idx[j] < me) ? 1u : 0u;
        if (rank == T - 1u) s_icut = me;
      }
      __syncthreads();
      icut = s_icut;
    }
  }
  for (uint32_t i = tid; i < n; i += 1024u) {
    float v = x[i];
    uint32_t key = (v > 0.f) ? __float_as_uint(v) : 0u;
    bool keep = (key > thr_key) || (key != 0u && key == thr_key && i <= icut);
    out[i] = keep ? v : 0.f;
  }
}

// Sparse scatter of kept candidates into the zeroed output.
__global__ __launch_bounds__(256) void k_scatter(
    const uint2* __restrict__ cand, const uint32_t* __restrict__ hdr,
    float* __restrict__ out, uint32_t cap) {
  if (hdr[HDR_FLAG] != 0u) return;
  uint32_t M = hdr[HDR_CURSOR]; if (M > cap) M = cap;
  uint32_t thr = hdr[HDR_THR], icut = hdr[HDR_ICUT];
  uint32_t stride = gridDim.x * blockDim.x;
  for (uint32_t i = blockIdx.x * blockDim.x + threadIdx.x; i < M; i += stride) {
    uint2 c = cand[i];
    if (c.x > thr || (c.x == thr && c.y <= icut)) out[c.y] = __uint_as_float(c.x);
  }
}

extern "C" void kernel_launch(void* const* d_in, const int* in_sizes, int n_in,
                              void* d_out, int out_size, void* d_ws, size_t ws_size,
                              hipStream_t stream) {
  const float* x = (const float*)d_in[0];
  const int* kptr = (const int*)d_in[1];
  float* out = (float*)d_out;
  uint32_t n = (uint32_t)in_sizes[0];
  uint32_t n4 = n >> 2;

  uint32_t* hdr = (uint32_t*)d_ws;
  uint32_t* ghist = (uint32_t*)((char*)d_ws + HIST_OFF);
  uint2* cand = (uint2*)((char*)d_ws + CAND_OFF);
  uint32_t cap = (ws_size > (size_t)CAND_OFF) ? (uint32_t)((ws_size - CAND_OFF) / 8) : 0u;

  if (cap < 131072u) {
    // ws too small for candidates: zero headers AND force the exact fallback.
    k_init<<<1, 256, 0, stream>>>(hdr, ghist, 1u);
  } else {
    // zero hdr (256B used) + ghist (8KB @ +4096) in one memset node
    hipMemsetAsync(d_ws, 0, 12288, stream);
  }
  const uint32_t HALF = 1024u;   // blocks per role; grid = 2*HALF
  k_scanzero<<<2u * HALF, 256, 0, stream>>>((float4*)out, out, (const float4*)x, x,
                                            cand, hdr, ghist, cap, n4, n, HALF);
  k_finish<<<1, 1024, 0, stream>>>(cand, hdr, ghist, kptr, x, out, cap, n);
  k_scatter<<<512, 256, 0, stream>>>(cand, hdr, out, cap);
}

// Round 8
// 477.532 us; speedup vs baseline: 1.0357x; 1.0357x over previous
//
#include <hip/hip_runtime.h>
#include <stdint.h>

// BatchTopK: x (1024, 65536) f32, keep global top k*1024 = 65536 of relu(x), zero rest.
//
// R13: R11 structure + NON-TEMPORAL LOADS in the scan. Single variable.
// Evidence: R12 role-split fusion regressed (495 vs 485) -> ours is BW-bound
// and arrangement-insensitive; write stream already at HW rate (memset 6.5TB/s).
// The scan reads 256MB at only ~2.5TB/s effective and three instruction-level
// restructures (R9/R10/R11) were all equivalent -> limit is the memory path.
// Theory: x (256MB) == L3 capacity; every miss does L3-fill+evict of lines the
// scan still needs (capacity thrash). FETCH=131MB each round = half-hits.
// nt LOADS bypass L3 allocation -> pure HBM streaming (~6.3TB/s read).
// (R6/R8's nt pathology was STORE-side write-combine; loads are a different path.)

#define HDR_CURSOR 0
#define HDR_FLAG   1
#define HDR_THR    2
#define HDR_ICUT   3
#define HIST_OFF   4096       // uint32 ghist[2048] at ws+4096
#define CAND_OFF   16384      // candidate buffer
#define NBINS      2048u
#define BUCKET_CAP 6144u
#define SCAN_STAGE 1024       // per-block candidate staging (expected ~44/block)
#define ROWS       1024u      // x.shape[0], fixed by the problem
#define SPEC       3.0f       // count(x>=3.0) ~ 90.6k >= K=65536
#define BASE_BITS  0x40400000u  // __float_as_uint(3.0f)

typedef float f32x4 __attribute__((ext_vector_type(4)));

__device__ __forceinline__ uint32_t bin_of(uint32_t key) {
  uint32_t off = key - BASE_BITS;        // key >= BASE_BITS guaranteed by SPEC filter
  uint32_t b = off >> 12;
  return b < NBINS ? b : (NBINS - 1u);
}

__device__ __forceinline__ float max4v(f32x4 a) {
  return fmaxf(fmaxf(a.x, a.y), fmaxf(a.z, a.w));
}

// Only used on the forced-fallback path (tiny workspace).
__global__ void k_init(uint32_t* hdr, uint32_t* ghist, uint32_t force_flag) {
  for (uint32_t i = threadIdx.x; i < 64u + NBINS; i += 256u) {
    if (i < 64u) hdr[i] = 0u;
    else ghist[i - 64u] = 0u;
  }
  if (threadIdx.x == 0u) hdr[HDR_FLAG] = force_flag;
}

__device__ __forceinline__ void push4v(f32x4 a, uint32_t gi,
                                       uint32_t* s_cnt, uint2* s_buf) {
  if (a.x >= SPEC) { uint32_t p = atomicAdd(s_cnt, 1u); if (p < SCAN_STAGE) s_buf[p] = make_uint2(__float_as_uint(a.x), gi); }
  if (a.y >= SPEC) { uint32_t p = atomicAdd(s_cnt, 1u); if (p < SCAN_STAGE) s_buf[p] = make_uint2(__float_as_uint(a.y), gi + 1u); }
  if (a.z >= SPEC) { uint32_t p = atomicAdd(s_cnt, 1u); if (p < SCAN_STAGE) s_buf[p] = make_uint2(__float_as_uint(a.z), gi + 2u); }
  if (a.w >= SPEC) { uint32_t p = atomicAdd(s_cnt, 1u); if (p < SCAN_STAGE) s_buf[p] = make_uint2(__float_as_uint(a.w), gi + 3u); }
}

// Read-only scan: wave-contiguous 4-deep NON-TEMPORAL loads (bypass L3
// allocation; stream from HBM). Ballot per float4 (~71% skip).
__global__ __launch_bounds__(256) void k_scan(
    const float4* __restrict__ x4, const float* __restrict__ x,
    uint2* __restrict__ cand, uint32_t* __restrict__ hdr,
    uint32_t* __restrict__ ghist,
    uint32_t cap, uint32_t n4, uint32_t n) {
  __shared__ uint32_t s_cnt;
  __shared__ uint32_t s_base;
  __shared__ uint2 s_buf[SCAN_STAGE];
  uint32_t tid = threadIdx.x;
  if (tid == 0u) s_cnt = 0u;
  __syncthreads();

  const f32x4* __restrict__ xv = (const f32x4*)x4;
  uint32_t lane = tid & 63u;
  uint32_t gwid = (blockIdx.x * blockDim.x + tid) >> 6;   // global wave id
  uint32_t nw   = (gridDim.x * blockDim.x) >> 6;          // total waves
  uint32_t nchunk = n4 >> 8;                              // 256-float4 chunks
  for (uint32_t c = gwid; c < nchunk; c += nw) {
    uint32_t base = c << 8;
    f32x4 a0 = __builtin_nontemporal_load(xv + base + lane);
    f32x4 a1 = __builtin_nontemporal_load(xv + base + 64u + lane);
    f32x4 a2 = __builtin_nontemporal_load(xv + base + 128u + lane);
    f32x4 a3 = __builtin_nontemporal_load(xv + base + 192u + lane);
    if (__ballot(max4v(a0) >= SPEC)) push4v(a0, (base + lane) * 4u, &s_cnt, s_buf);
    if (__ballot(max4v(a1) >= SPEC)) push4v(a1, (base + 64u + lane) * 4u, &s_cnt, s_buf);
    if (__ballot(max4v(a2) >= SPEC)) push4v(a2, (base + 128u + lane) * 4u, &s_cnt, s_buf);
    if (__ballot(max4v(a3) >= SPEC)) push4v(a3, (base + 192u + lane) * 4u, &s_cnt, s_buf);
  }
  // remainder float4s (none for the bench shape) + scalar tail
  uint32_t rem0 = nchunk << 8;
  if (blockIdx.x == 0u) {
    for (uint32_t i = rem0 + tid; i < n4; i += blockDim.x) {
      f32x4 a = xv[i];
      if (__ballot(max4v(a) >= SPEC)) push4v(a, i * 4u, &s_cnt, s_buf);
    }
    uint32_t tail0 = n4 * 4u;
    if (tid < (n - tail0)) {
      uint32_t gi = tail0 + tid;
      float v = x[gi];
      if (v >= SPEC) { uint32_t p = atomicAdd(&s_cnt, 1u); if (p < SCAN_STAGE) s_buf[p] = make_uint2(__float_as_uint(v), gi); }
    }
  }
  __syncthreads();
  uint32_t cnt = s_cnt;
  if (cnt == 0u) return;
  uint32_t wcnt = cnt < (uint32_t)SCAN_STAGE ? cnt : (uint32_t)SCAN_STAGE;
  if (tid == 0u) {
    s_base = atomicAdd(&hdr[HDR_CURSOR], cnt);  // true total (drops flagged)
    if (cnt > (uint32_t)SCAN_STAGE) atomicOr(&hdr[HDR_FLAG], 1u);
  }
  __syncthreads();
  uint32_t base = s_base;
  for (uint32_t j = tid; j < wcnt; j += blockDim.x) {
    uint32_t gidx = base + j;
    if (gidx < cap) {
      uint2 c = s_buf[j];
      cand[gidx] = c;
      atomicAdd(&ghist[bin_of(c.x)], 1u);   // ~44/block, spread over 2048 words
    }
  }
  if (tid == 0u && base + wcnt > cap) atomicOr(&hdr[HDR_FLAG], 1u);
}

// Single block: select (2048-bin suffix scan + bucket collect + exact rank);
// on any abort, the exact full-radix fallback runs inline in the same block.
__global__ __launch_bounds__(1024) void k_finish(
    const uint2* __restrict__ cand, uint32_t* __restrict__ hdr,
    const uint32_t* __restrict__ ghist, const int* __restrict__ kptr,
    const float* __restrict__ x, float* __restrict__ out,
    uint32_t cap, uint32_t n) {
  __shared__ __align__(16) uint8_t smem[57344];          // 56 KB union
  uint32_t* h      = (uint32_t*)smem;                    // select hist / fb hist
  uint2*    bkt    = (uint2*)(smem + 8192);              // select bucket (48KB)
  uint32_t* eq_idx = (uint32_t*)(smem + 8192);           // fb eq-scan (16KB, aliases bkt)
  __shared__ uint32_t s_sel, s_rank, s_bcnt, s_need, s_found, s_eqcnt, s_icut;
  uint32_t tid = threadIdx.x;
  uint32_t K = (uint32_t)kptr[0] * ROWS;
  uint32_t M = hdr[HDR_CURSOR];
  if (tid == 0u) s_need = 0u;
  __syncthreads();

  // ---------------- select phase (block-uniform branching) ----------------
  bool skip_sel = (hdr[HDR_FLAG] != 0u || M > cap || M < K);
  if (skip_sel) {
    if (tid == 0u) s_need = 1u;
  } else if (K == 0u) {
    // keep nothing; candidate keys are finite positive floats < 0xFFFFFFFF
    if (tid == 0u) { hdr[HDR_THR] = 0xFFFFFFFFu; hdr[HDR_ICUT] = 0xFFFFFFFFu; }
    return;
  } else {
    h[tid] = ghist[tid];
    h[tid + 1024u] = ghist[tid + 1024u];
    if (tid == 0u) s_bcnt = 0u;
    __syncthreads();
    // wave 0: suffix scan over 2048 bins to find the bin holding rank K
    if (tid < 64u) {
      uint32_t seg = NBINS >> 6;           // 32 bins per lane
      uint32_t base = tid * seg;
      uint32_t lanesum = 0u;
      for (uint32_t j = 0; j < seg; ++j) lanesum += h[base + j];
      uint32_t s = lanesum;                // inclusive suffix scan across lanes
      for (int d = 1; d < 64; d <<= 1) {
        uint32_t v = (uint32_t)__shfl_down((int)s, d, 64);
        if ((int)tid + d < 64) s += v;
      }
      uint32_t above = s - lanesum;        // total count in lanes > tid
      if (above < K && above + lanesum >= K) {   // exactly one lane matches
        uint32_t r = K - above;
        uint32_t cum = 0u;
        for (int j = (int)seg - 1; j >= 0; --j) {
          uint32_t c = h[base + (uint32_t)j];
          if (cum + c >= r) { s_sel = base + (uint32_t)j; s_rank = r - cum; break; }
          cum += c;
        }
      }
    }
    __syncthreads();
    uint32_t bsel = s_sel;
    uint32_t r = s_rank;                   // 1-indexed rank inside the bin
    uint32_t E = h[bsel];
    if (bsel == NBINS - 1u || E > BUCKET_CAP) {  // clamp bin or oversized bucket
      if (tid == 0u) s_need = 1u;
    } else {
      // collect candidates in bin bsel (x4 unrolled, 8 keys/iter)
      const uint4* __restrict__ cand4 = (const uint4*)cand;
      uint32_t M2 = M >> 1;
      uint32_t j = tid;
      for (; j + 3072u < M2; j += 4096u) {
        uint4 c0 = cand4[j];
        uint4 c1 = cand4[j + 1024u];
        uint4 c2 = cand4[j + 2048u];
        uint4 c3 = cand4[j + 3072u];
        if (bin_of(c0.x) == bsel) { uint32_t p = atomicAdd(&s_bcnt, 1u); if (p < BUCKET_CAP) bkt[p] = make_uint2(c0.x, c0.y); }
        if (bin_of(c0.z) == bsel) { uint32_t p = atomicAdd(&s_bcnt, 1u); if (p < BUCKET_CAP) bkt[p] = make_uint2(c0.z, c0.w); }
        if (bin_of(c1.x) == bsel) { uint32_t p = atomicAdd(&s_bcnt, 1u); if (p < BUCKET_CAP) bkt[p] = make_uint2(c1.x, c1.y); }
        if (bin_of(c1.z) == bsel) { uint32_t p = atomicAdd(&s_bcnt, 1u); if (p < BUCKET_CAP) bkt[p] = make_uint2(c1.z, c1.w); }
        if (bin_of(c2.x) == bsel) { uint32_t p = atomicAdd(&s_bcnt, 1u); if (p < BUCKET_CAP) bkt[p] = make_uint2(c2.x, c2.y); }
        if (bin_of(c2.z) == bsel) { uint32_t p = atomicAdd(&s_bcnt, 1u); if (p < BUCKET_CAP) bkt[p] = make_uint2(c2.z, c2.w); }
        if (bin_of(c3.x) == bsel) { uint32_t p = atomicAdd(&s_bcnt, 1u); if (p < BUCKET_CAP) bkt[p] = make_uint2(c3.x, c3.y); }
        if (bin_of(c3.z) == bsel) { uint32_t p = atomicAdd(&s_bcnt, 1u); if (p < BUCKET_CAP) bkt[p] = make_uint2(c3.z, c3.w); }
      }
      for (; j < M2; j += 1024u) {
        uint4 c = cand4[j];
        if (bin_of(c.x) == bsel) { uint32_t p = atomicAdd(&s_bcnt, 1u); if (p < BUCKET_CAP) bkt[p] = make_uint2(c.x, c.y); }
        if (bin_of(c.z) == bsel) { uint32_t p = atomicAdd(&s_bcnt, 1u); if (p < BUCKET_CAP) bkt[p] = make_uint2(c.z, c.w); }
      }
      if (tid == 0u && (M & 1u)) {
        uint2 c = cand[M - 1u];
        if (bin_of(c.x) == bsel) { uint32_t p = atomicAdd(&s_bcnt, 1u); if (p < BUCKET_CAP) bkt[p] = c; }
      }
      __syncthreads();
      // exact selection: entry with composite rank r-1 (key desc, idx asc)
      for (uint32_t e = tid; e < E; e += 1024u) {
        uint2 me = bkt[e];
        uint32_t rank = 0u;
        for (uint32_t jj = 0; jj < E; ++jj) {
          uint2 o = bkt[jj];
          rank += (o.x > me.x || (o.x == me.x && o.y < me.y)) ? 1u : 0u;
        }
        if (rank == r - 1u) { hdr[HDR_THR] = me.x; hdr[HDR_ICUT] = me.y; }
      }
    }
  }
  __syncthreads();
  if (s_need == 0u) return;
  if (tid == 0u) hdr[HDR_FLAG] = 1u;   // k_scatter will skip

  // ---------------- exact fallback (inline, same block) ----------------
  uint32_t prefix = 0u;
  uint32_t R = K;
  bool zero_thr = (K == 0u);
  for (int lvl = 0; lvl < 3 && !zero_thr; ++lvl) {
    uint32_t shift = (lvl == 0) ? 21u : (lvl == 1 ? 10u : 0u);
    uint32_t nb = (lvl == 2) ? 1024u : 2048u;
    for (uint32_t b = tid; b < nb; b += 1024u) h[b] = 0u;
    __syncthreads();
    for (uint32_t i = tid; i < n; i += 1024u) {
      float v = x[i];
      uint32_t key = (v > 0.f) ? __float_as_uint(v) : 0u;
      bool valid = (key != 0u);
      if (lvl == 1) valid = valid && ((key >> 21) == prefix);
      if (lvl == 2) valid = valid && ((key >> 10) == prefix);
      if (valid) atomicAdd(&h[(key >> shift) & (nb - 1u)], 1u);
    }
    __syncthreads();
    if (tid == 0u) {
      uint32_t cum = 0u, sel = 0u, rr = R, found = 0u;
      for (int b = (int)nb - 1; b >= 0; --b) {
        uint32_t c = h[b];
        if (cum + c >= R) { sel = (uint32_t)b; rr = R - cum; found = 1u; break; }
        cum += c;
      }
      s_sel = sel; s_rank = rr; s_found = found;
    }
    __syncthreads();
    if (s_found == 0u) {
      zero_thr = true;  // fewer than K positives: keep all positives
    } else {
      uint32_t sel = s_sel;
      R = s_rank;
      if (lvl == 0) prefix = sel;
      else if (lvl == 1) prefix = (prefix << 11) | sel;
      else prefix = (prefix << 10) | sel;
    }
    __syncthreads();
  }
  uint32_t thr_key = zero_thr ? 0u : prefix;
  uint32_t icut = 0xFFFFFFFFu;
  if (!zero_thr) {
    uint32_t E2 = h[thr_key & 1023u];
    uint32_t T = R;
    if (T < E2) {
      if (tid == 0u) { s_eqcnt = 0u; s_icut = 0xFFFFFFFFu; }
      __syncthreads();
      for (uint32_t i = tid; i < n; i += 1024u) {
        float v = x[i];
        if (v > 0.f && __float_as_uint(v) == thr_key) {
          uint32_t p = atomicAdd(&s_eqcnt, 1u);
          if (p < 4096u) eq_idx[p] = i;
        }
      }
      __syncthreads();
      uint32_t ec = s_eqcnt < 4096u ? s_eqcnt : 4096u;
      for (uint32_t e = tid; e < ec; e += 1024u) {
        uint32_t me = eq_idx[e];
        uint32_t rank = 0u;
        for (uint32_t j = 0; j < ec; ++j) rank += (eq_idx[j] < me) ? 1u : 0u;
        if (rank == T - 1u) s_icut = me;
      }
      __syncthreads();
      icut = s_icut;
    }
  }
  for (uint32_t i = tid; i < n; i += 1024u) {
    float v = x[i];
    uint32_t key = (v > 0.f) ? __float_as_uint(v) : 0u;
    bool keep = (key > thr_key) || (key != 0u && key == thr_key && i <= icut);
    out[i] = keep ? v : 0.f;
  }
}

// Sparse scatter of kept candidates into the zeroed output.
__global__ __launch_bounds__(256) void k_scatter(
    const uint2* __restrict__ cand, const uint32_t* __restrict__ hdr,
    float* __restrict__ out, uint32_t cap) {
  if (hdr[HDR_FLAG] != 0u) return;
  uint32_t M = hdr[HDR_CURSOR]; if (M > cap) M = cap;
  uint32_t thr = hdr[HDR_THR], icut = hdr[HDR_ICUT];
  uint32_t stride = gridDim.x * blockDim.x;
  for (uint32_t i = blockIdx.x * blockDim.x + threadIdx.x; i < M; i += stride) {
    uint2 c = cand[i];
    if (c.x > thr || (c.x == thr && c.y <= icut)) out[c.y] = __uint_as_float(c.x);
  }
}

extern "C" void kernel_launch(void* const* d_in, const int* in_sizes, int n_in,
                              void* d_out, int out_size, void* d_ws, size_t ws_size,
                              hipStream_t stream) {
  const float* x = (const float*)d_in[0];
  const int* kptr = (const int*)d_in[1];
  float* out = (float*)d_out;
  uint32_t n = (uint32_t)in_sizes[0];
  uint32_t n4 = n >> 2;

  uint32_t* hdr = (uint32_t*)d_ws;
  uint32_t* ghist = (uint32_t*)((char*)d_ws + HIST_OFF);
  uint2* cand = (uint2*)((char*)d_ws + CAND_OFF);
  uint32_t cap = (ws_size > (size_t)CAND_OFF) ? (uint32_t)((ws_size - CAND_OFF) / 8) : 0u;

  if (cap < 131072u) {
    // ws too small for candidates: zero headers AND force the exact fallback.
    k_init<<<1, 256, 0, stream>>>(hdr, ghist, 1u);
  } else {
    // zero hdr (256B used) + ghist (8KB @ +4096) in one memset node
    hipMemsetAsync(d_ws, 0, 12288, stream);
  }
  k_scan<<<2048, 256, 0, stream>>>((const float4*)x, x, cand, hdr, ghist, cap, n4, n);
  // Zero the output via the rocclr fill path (plain stores, 6.5 TB/s measured).
  hipMemsetAsync(out, 0, (size_t)n * 4u, stream);
  k_finish<<<1, 1024, 0, stream>>>(cand, hdr, ghist, kptr, x, out, cap, n);
  k_scatter<<<512, 256, 0, stream>>>(cand, hdr, out, cap);
}

// Round 9
// 474.000 us; speedup vs baseline: 1.0435x; 1.0075x over previous
//
#include <hip/hip_runtime.h>
#include <stdint.h>

// BatchTopK: x (1024, 65536) f32, keep global top k*1024 = 65536 of relu(x), zero rest.
//
// R14: R13 + scan depth 4 -> 8 (wave-contiguous nt loads). Single variable.
// Ledger: R13 477.5us = ~332 fill floor + ~41 memset-out + ~15 small + ~89 scan
// (2.9 TB/s read). Fill hits 6.5 TB/s at 10% occupancy -> saturation is about
// the memory path. A scanning wave waits on each load before its ballot, so
// loads-in-flight/wave ~= unroll depth. Depth has never been tested
// uncontaminated: R7's 8-deep was 8MB-strided (page thrash); R10/R11/R13 are
// contiguous but 1-4 deep. If depth is the limiter, 8-deep contiguous doubles
// effective read BW; if neutral, the dependent-read ceiling is real -> roofline.

#define HDR_CURSOR 0
#define HDR_FLAG   1
#define HDR_THR    2
#define HDR_ICUT   3
#define HIST_OFF   4096       // uint32 ghist[2048] at ws+4096
#define CAND_OFF   16384      // candidate buffer
#define NBINS      2048u
#define BUCKET_CAP 6144u
#define SCAN_STAGE 1024       // per-block candidate staging (expected ~44/block)
#define ROWS       1024u      // x.shape[0], fixed by the problem
#define SPEC       3.0f       // count(x>=3.0) ~ 90.6k >= K=65536
#define BASE_BITS  0x40400000u  // __float_as_uint(3.0f)

typedef float f32x4 __attribute__((ext_vector_type(4)));

__device__ __forceinline__ uint32_t bin_of(uint32_t key) {
  uint32_t off = key - BASE_BITS;        // key >= BASE_BITS guaranteed by SPEC filter
  uint32_t b = off >> 12;
  return b < NBINS ? b : (NBINS - 1u);
}

__device__ __forceinline__ float max4v(f32x4 a) {
  return fmaxf(fmaxf(a.x, a.y), fmaxf(a.z, a.w));
}

// Only used on the forced-fallback path (tiny workspace).
__global__ void k_init(uint32_t* hdr, uint32_t* ghist, uint32_t force_flag) {
  for (uint32_t i = threadIdx.x; i < 64u + NBINS; i += 256u) {
    if (i < 64u) hdr[i] = 0u;
    else ghist[i - 64u] = 0u;
  }
  if (threadIdx.x == 0u) hdr[HDR_FLAG] = force_flag;
}

__device__ __forceinline__ void push4v(f32x4 a, uint32_t gi,
                                       uint32_t* s_cnt, uint2* s_buf) {
  if (a.x >= SPEC) { uint32_t p = atomicAdd(s_cnt, 1u); if (p < SCAN_STAGE) s_buf[p] = make_uint2(__float_as_uint(a.x), gi); }
  if (a.y >= SPEC) { uint32_t p = atomicAdd(s_cnt, 1u); if (p < SCAN_STAGE) s_buf[p] = make_uint2(__float_as_uint(a.y), gi + 1u); }
  if (a.z >= SPEC) { uint32_t p = atomicAdd(s_cnt, 1u); if (p < SCAN_STAGE) s_buf[p] = make_uint2(__float_as_uint(a.z), gi + 2u); }
  if (a.w >= SPEC) { uint32_t p = atomicAdd(s_cnt, 1u); if (p < SCAN_STAGE) s_buf[p] = make_uint2(__float_as_uint(a.w), gi + 3u); }
}

// Read-only scan: wave-contiguous 8-deep NON-TEMPORAL loads (8KB contiguous
// per wave, 8 loads in flight). Ballot per float4 (~71% skip).
__global__ __launch_bounds__(256) void k_scan(
    const float4* __restrict__ x4, const float* __restrict__ x,
    uint2* __restrict__ cand, uint32_t* __restrict__ hdr,
    uint32_t* __restrict__ ghist,
    uint32_t cap, uint32_t n4, uint32_t n) {
  __shared__ uint32_t s_cnt;
  __shared__ uint32_t s_base;
  __shared__ uint2 s_buf[SCAN_STAGE];
  uint32_t tid = threadIdx.x;
  if (tid == 0u) s_cnt = 0u;
  __syncthreads();

  const f32x4* __restrict__ xv = (const f32x4*)x4;
  uint32_t lane = tid & 63u;
  uint32_t gwid = (blockIdx.x * blockDim.x + tid) >> 6;   // global wave id
  uint32_t nw   = (gridDim.x * blockDim.x) >> 6;          // total waves
  uint32_t nchunk = n4 >> 9;                              // 512-float4 chunks
  for (uint32_t c = gwid; c < nchunk; c += nw) {
    uint32_t base = c << 9;
    f32x4 a0 = __builtin_nontemporal_load(xv + base + lane);
    f32x4 a1 = __builtin_nontemporal_load(xv + base + 64u + lane);
    f32x4 a2 = __builtin_nontemporal_load(xv + base + 128u + lane);
    f32x4 a3 = __builtin_nontemporal_load(xv + base + 192u + lane);
    f32x4 a4 = __builtin_nontemporal_load(xv + base + 256u + lane);
    f32x4 a5 = __builtin_nontemporal_load(xv + base + 320u + lane);
    f32x4 a6 = __builtin_nontemporal_load(xv + base + 384u + lane);
    f32x4 a7 = __builtin_nontemporal_load(xv + base + 448u + lane);
    if (__ballot(max4v(a0) >= SPEC)) push4v(a0, (base + lane) * 4u, &s_cnt, s_buf);
    if (__ballot(max4v(a1) >= SPEC)) push4v(a1, (base + 64u + lane) * 4u, &s_cnt, s_buf);
    if (__ballot(max4v(a2) >= SPEC)) push4v(a2, (base + 128u + lane) * 4u, &s_cnt, s_buf);
    if (__ballot(max4v(a3) >= SPEC)) push4v(a3, (base + 192u + lane) * 4u, &s_cnt, s_buf);
    if (__ballot(max4v(a4) >= SPEC)) push4v(a4, (base + 256u + lane) * 4u, &s_cnt, s_buf);
    if (__ballot(max4v(a5) >= SPEC)) push4v(a5, (base + 320u + lane) * 4u, &s_cnt, s_buf);
    if (__ballot(max4v(a6) >= SPEC)) push4v(a6, (base + 384u + lane) * 4u, &s_cnt, s_buf);
    if (__ballot(max4v(a7) >= SPEC)) push4v(a7, (base + 448u + lane) * 4u, &s_cnt, s_buf);
  }
  // remainder float4s (none for the bench shape) + scalar tail
  uint32_t rem0 = nchunk << 9;
  if (blockIdx.x == 0u) {
    for (uint32_t i = rem0 + tid; i < n4; i += blockDim.x) {
      f32x4 a = xv[i];
      if (__ballot(max4v(a) >= SPEC)) push4v(a, i * 4u, &s_cnt, s_buf);
    }
    uint32_t tail0 = n4 * 4u;
    if (tid < (n - tail0)) {
      uint32_t gi = tail0 + tid;
      float v = x[gi];
      if (v >= SPEC) { uint32_t p = atomicAdd(&s_cnt, 1u); if (p < SCAN_STAGE) s_buf[p] = make_uint2(__float_as_uint(v), gi); }
    }
  }
  __syncthreads();
  uint32_t cnt = s_cnt;
  if (cnt == 0u) return;
  uint32_t wcnt = cnt < (uint32_t)SCAN_STAGE ? cnt : (uint32_t)SCAN_STAGE;
  if (tid == 0u) {
    s_base = atomicAdd(&hdr[HDR_CURSOR], cnt);  // true total (drops flagged)
    if (cnt > (uint32_t)SCAN_STAGE) atomicOr(&hdr[HDR_FLAG], 1u);
  }
  __syncthreads();
  uint32_t base = s_base;
  for (uint32_t j = tid; j < wcnt; j += blockDim.x) {
    uint32_t gidx = base + j;
    if (gidx < cap) {
      uint2 c = s_buf[j];
      cand[gidx] = c;
      atomicAdd(&ghist[bin_of(c.x)], 1u);   // ~44/block, spread over 2048 words
    }
  }
  if (tid == 0u && base + wcnt > cap) atomicOr(&hdr[HDR_FLAG], 1u);
}

// Single block: select (2048-bin suffix scan + bucket collect + exact rank);
// on any abort, the exact full-radix fallback runs inline in the same block.
__global__ __launch_bounds__(1024) void k_finish(
    const uint2* __restrict__ cand, uint32_t* __restrict__ hdr,
    const uint32_t* __restrict__ ghist, const int* __restrict__ kptr,
    const float* __restrict__ x, float* __restrict__ out,
    uint32_t cap, uint32_t n) {
  __shared__ __align__(16) uint8_t smem[57344];          // 56 KB union
  uint32_t* h      = (uint32_t*)smem;                    // select hist / fb hist
  uint2*    bkt    = (uint2*)(smem + 8192);              // select bucket (48KB)
  uint32_t* eq_idx = (uint32_t*)(smem + 8192);           // fb eq-scan (16KB, aliases bkt)
  __shared__ uint32_t s_sel, s_rank, s_bcnt, s_need, s_found, s_eqcnt, s_icut;
  uint32_t tid = threadIdx.x;
  uint32_t K = (uint32_t)kptr[0] * ROWS;
  uint32_t M = hdr[HDR_CURSOR];
  if (tid == 0u) s_need = 0u;
  __syncthreads();

  // ---------------- select phase (block-uniform branching) ----------------
  bool skip_sel = (hdr[HDR_FLAG] != 0u || M > cap || M < K);
  if (skip_sel) {
    if (tid == 0u) s_need = 1u;
  } else if (K == 0u) {
    // keep nothing; candidate keys are finite positive floats < 0xFFFFFFFF
    if (tid == 0u) { hdr[HDR_THR] = 0xFFFFFFFFu; hdr[HDR_ICUT] = 0xFFFFFFFFu; }
    return;
  } else {
    h[tid] = ghist[tid];
    h[tid + 1024u] = ghist[tid + 1024u];
    if (tid == 0u) s_bcnt = 0u;
    __syncthreads();
    // wave 0: suffix scan over 2048 bins to find the bin holding rank K
    if (tid < 64u) {
      uint32_t seg = NBINS >> 6;           // 32 bins per lane
      uint32_t base = tid * seg;
      uint32_t lanesum = 0u;
      for (uint32_t j = 0; j < seg; ++j) lanesum += h[base + j];
      uint32_t s = lanesum;                // inclusive suffix scan across lanes
      for (int d = 1; d < 64; d <<= 1) {
        uint32_t v = (uint32_t)__shfl_down((int)s, d, 64);
        if ((int)tid + d < 64) s += v;
      }
      uint32_t above = s - lanesum;        // total count in lanes > tid
      if (above < K && above + lanesum >= K) {   // exactly one lane matches
        uint32_t r = K - above;
        uint32_t cum = 0u;
        for (int j = (int)seg - 1; j >= 0; --j) {
          uint32_t c = h[base + (uint32_t)j];
          if (cum + c >= r) { s_sel = base + (uint32_t)j; s_rank = r - cum; break; }
          cum += c;
        }
      }
    }
    __syncthreads();
    uint32_t bsel = s_sel;
    uint32_t r = s_rank;                   // 1-indexed rank inside the bin
    uint32_t E = h[bsel];
    if (bsel == NBINS - 1u || E > BUCKET_CAP) {  // clamp bin or oversized bucket
      if (tid == 0u) s_need = 1u;
    } else {
      // collect candidates in bin bsel (x4 unrolled, 8 keys/iter)
      const uint4* __restrict__ cand4 = (const uint4*)cand;
      uint32_t M2 = M >> 1;
      uint32_t j = tid;
      for (; j + 3072u < M2; j += 4096u) {
        uint4 c0 = cand4[j];
        uint4 c1 = cand4[j + 1024u];
        uint4 c2 = cand4[j + 2048u];
        uint4 c3 = cand4[j + 3072u];
        if (bin_of(c0.x) == bsel) { uint32_t p = atomicAdd(&s_bcnt, 1u); if (p < BUCKET_CAP) bkt[p] = make_uint2(c0.x, c0.y); }
        if (bin_of(c0.z) == bsel) { uint32_t p = atomicAdd(&s_bcnt, 1u); if (p < BUCKET_CAP) bkt[p] = make_uint2(c0.z, c0.w); }
        if (bin_of(c1.x) == bsel) { uint32_t p = atomicAdd(&s_bcnt, 1u); if (p < BUCKET_CAP) bkt[p] = make_uint2(c1.x, c1.y); }
        if (bin_of(c1.z) == bsel) { uint32_t p = atomicAdd(&s_bcnt, 1u); if (p < BUCKET_CAP) bkt[p] = make_uint2(c1.z, c1.w); }
        if (bin_of(c2.x) == bsel) { uint32_t p = atomicAdd(&s_bcnt, 1u); if (p < BUCKET_CAP) bkt[p] = make_uint2(c2.x, c2.y); }
        if (bin_of(c2.z) == bsel) { uint32_t p = atomicAdd(&s_bcnt, 1u); if (p < BUCKET_CAP) bkt[p] = make_uint2(c2.z, c2.w); }
        if (bin_of(c3.x) == bsel) { uint32_t p = atomicAdd(&s_bcnt, 1u); if (p < BUCKET_CAP) bkt[p] = make_uint2(c3.x, c3.y); }
        if (bin_of(c3.z) == bsel) { uint32_t p = atomicAdd(&s_bcnt, 1u); if (p < BUCKET_CAP) bkt[p] = make_uint2(c3.z, c3.w); }
      }
      for (; j < M2; j += 1024u) {
        uint4 c = cand4[j];
        if (bin_of(c.x) == bsel) { uint32_t p = atomicAdd(&s_bcnt, 1u); if (p < BUCKET_CAP) bkt[p] = make_uint2(c.x, c.y); }
        if (bin_of(c.z) == bsel) { uint32_t p = atomicAdd(&s_bcnt, 1u); if (p < BUCKET_CAP) bkt[p] = make_uint2(c.z, c.w); }
      }
      if (tid == 0u && (M & 1u)) {
        uint2 c = cand[M - 1u];
        if (bin_of(c.x) == bsel) { uint32_t p = atomicAdd(&s_bcnt, 1u); if (p < BUCKET_CAP) bkt[p] = c; }
      }
      __syncthreads();
      // exact selection: entry with composite rank r-1 (key desc, idx asc)
      for (uint32_t e = tid; e < E; e += 1024u) {
        uint2 me = bkt[e];
        uint32_t rank = 0u;
        for (uint32_t jj = 0; jj < E; ++jj) {
          uint2 o = bkt[jj];
          rank += (o.x > me.x || (o.x == me.x && o.y < me.y)) ? 1u : 0u;
        }
        if (rank == r - 1u) { hdr[HDR_THR] = me.x; hdr[HDR_ICUT] = me.y; }
      }
    }
  }
  __syncthreads();
  if (s_need == 0u) return;
  if (tid == 0u) hdr[HDR_FLAG] = 1u;   // k_scatter will skip

  // ---------------- exact fallback (inline, same block) ----------------
  uint32_t prefix = 0u;
  uint32_t R = K;
  bool zero_thr = (K == 0u);
  for (int lvl = 0; lvl < 3 && !zero_thr; ++lvl) {
    uint32_t shift = (lvl == 0) ? 21u : (lvl == 1 ? 10u : 0u);
    uint32_t nb = (lvl == 2) ? 1024u : 2048u;
    for (uint32_t b = tid; b < nb; b += 1024u) h[b] = 0u;
    __syncthreads();
    for (uint32_t i = tid; i < n; i += 1024u) {
      float v = x[i];
      uint32_t key = (v > 0.f) ? __float_as_uint(v) : 0u;
      bool valid = (key != 0u);
      if (lvl == 1) valid = valid && ((key >> 21) == prefix);
      if (lvl == 2) valid = valid && ((key >> 10) == prefix);
      if (valid) atomicAdd(&h[(key >> shift) & (nb - 1u)], 1u);
    }
    __syncthreads();
    if (tid == 0u) {
      uint32_t cum = 0u, sel = 0u, rr = R, found = 0u;
      for (int b = (int)nb - 1; b >= 0; --b) {
        uint32_t c = h[b];
        if (cum + c >= R) { sel = (uint32_t)b; rr = R - cum; found = 1u; break; }
        cum += c;
      }
      s_sel = sel; s_rank = rr; s_found = found;
    }
    __syncthreads();
    if (s_found == 0u) {
      zero_thr = true;  // fewer than K positives: keep all positives
    } else {
      uint32_t sel = s_sel;
      R = s_rank;
      if (lvl == 0) prefix = sel;
      else if (lvl == 1) prefix = (prefix << 11) | sel;
      else prefix = (prefix << 10) | sel;
    }
    __syncthreads();
  }
  uint32_t thr_key = zero_thr ? 0u : prefix;
  uint32_t icut = 0xFFFFFFFFu;
  if (!zero_thr) {
    uint32_t E2 = h[thr_key & 1023u];
    uint32_t T = R;
    if (T < E2) {
      if (tid == 0u) { s_eqcnt = 0u; s_icut = 0xFFFFFFFFu; }
      __syncthreads();
      for (uint32_t i = tid; i < n; i += 1024u) {
        float v = x[i];
        if (v > 0.f && __float_as_uint(v) == thr_key) {
          uint32_t p = atomicAdd(&s_eqcnt, 1u);
          if (p < 4096u) eq_idx[p] = i;
        }
      }
      __syncthreads();
      uint32_t ec = s_eqcnt < 4096u ? s_eqcnt : 4096u;
      for (uint32_t e = tid; e < ec; e += 1024u) {
        uint32_t me = eq_idx[e];
        uint32_t rank = 0u;
        for (uint32_t j = 0; j < ec; ++j) rank += (eq_idx[j] < me) ? 1u : 0u;
        if (rank == T - 1u) s_icut = me;
      }
      __syncthreads();
      icut = s_icut;
    }
  }
  for (uint32_t i = tid; i < n; i += 1024u) {
    float v = x[i];
    uint32_t key = (v > 0.f) ? __float_as_uint(v) : 0u;
    bool keep = (key > thr_key) || (key != 0u && key == thr_key && i <= icut);
    out[i] = keep ? v : 0.f;
  }
}

// Sparse scatter of kept candidates into the zeroed output.
__global__ __launch_bounds__(256) void k_scatter(
    const uint2* __restrict__ cand, const uint32_t* __restrict__ hdr,
    float* __restrict__ out, uint32_t cap) {
  if (hdr[HDR_FLAG] != 0u) return;
  uint32_t M = hdr[HDR_CURSOR]; if (M > cap) M = cap;
  uint32_t thr = hdr[HDR_THR], icut = hdr[HDR_ICUT];
  uint32_t stride = gridDim.x * blockDim.x;
  for (uint32_t i = blockIdx.x * blockDim.x + threadIdx.x; i < M; i += stride) {
    uint2 c = cand[i];
    if (c.x > thr || (c.x == thr && c.y <= icut)) out[c.y] = __uint_as_float(c.x);
  }
}

extern "C" void kernel_launch(void* const* d_in, const int* in_sizes, int n_in,
                              void* d_out, int out_size, void* d_ws, size_t ws_size,
                              hipStream_t stream) {
  const float* x = (const float*)d_in[0];
  const int* kptr = (const int*)d_in[1];
  float* out = (float*)d_out;
  uint32_t n = (uint32_t)in_sizes[0];
  uint32_t n4 = n >> 2;

  uint32_t* hdr = (uint32_t*)d_ws;
  uint32_t* ghist = (uint32_t*)((char*)d_ws + HIST_OFF);
  uint2* cand = (uint2*)((char*)d_ws + CAND_OFF);
  uint32_t cap = (ws_size > (size_t)CAND_OFF) ? (uint32_t)((ws_size - CAND_OFF) / 8) : 0u;

  if (cap < 131072u) {
    // ws too small for candidates: zero headers AND force the exact fallback.
    k_init<<<1, 256, 0, stream>>>(hdr, ghist, 1u);
  } else {
    // zero hdr (256B used) + ghist (8KB @ +4096) in one memset node
    hipMemsetAsync(d_ws, 0, 12288, stream);
  }
  k_scan<<<2048, 256, 0, stream>>>((const float4*)x, x, cand, hdr, ghist, cap, n4, n);
  // Zero the output via the rocclr fill path (plain stores, 6.5 TB/s measured).
  hipMemsetAsync(out, 0, (size_t)n * 4u, stream);
  k_finish<<<1, 1024, 0, stream>>>(cand, hdr, ghist, kptr, x, out, cap, n);
  k_scatter<<<512, 256, 0, stream>>>(cand, hdr, out, cap);
}